// Round 8
// baseline (470.287 us; speedup 1.0000x reference)
//
#include <hip/hip_runtime.h>

constexpr int N_  = 10000;
constexpr int F_  = 128;
constexpr int E_  = 160000;
constexpr int BT_ = 4;            // B*T
constexpr int M_  = N_ * BT_;     // 40000 rows of [F]
constexpr int CAP = 64;           // bucket capacity per node (deg ~ Poisson(16))
constexpr int WT_ = 2500;         // 16-row wave-tiles (4 nodes each)
constexpr int GRID = 512;         // 2 blocks/CU -> all blocks co-resident

typedef __attribute__((ext_vector_type(8))) short bf16x8;   // 8 bf16 in 4 VGPRs
typedef __attribute__((ext_vector_type(4))) float f32x4;
typedef __attribute__((ext_vector_type(8))) unsigned short u16x8;

static __device__ inline float bf2f(unsigned short u) {
    union { unsigned int i; float f; } v; v.i = ((unsigned int)u) << 16; return v.f;
}
static __device__ inline unsigned short f2bf(float f) {
    union { float f; unsigned int i; } v; v.f = f;
    unsigned int x = v.i;
    return (unsigned short)((x + 0x7fffu + ((x >> 16) & 1u)) >> 16);  // RNE
}

// Manual grid barrier: generation counter, device-scope atomics.
// Safe because all GRID blocks are co-resident (2 blocks/CU by launch bounds).
static __device__ inline void gridbar(int* __restrict__ cnt, int* __restrict__ gen) {
    __syncthreads();
    if (threadIdx.x == 0) {
        __threadfence();     // release: make prior writes device-visible
        int g = __hip_atomic_load(gen, __ATOMIC_RELAXED, __HIP_MEMORY_SCOPE_AGENT);
        int v = __hip_atomic_fetch_add(cnt, 1, __ATOMIC_ACQ_REL, __HIP_MEMORY_SCOPE_AGENT);
        if (v == GRID - 1) {
            __hip_atomic_store(cnt, 0, __ATOMIC_RELAXED, __HIP_MEMORY_SCOPE_AGENT);
            __hip_atomic_fetch_add(gen, 1, __ATOMIC_ACQ_REL, __HIP_MEMORY_SCOPE_AGENT);
        } else {
            while (__hip_atomic_load(gen, __ATOMIC_RELAXED,
                                     __HIP_MEMORY_SCOPE_AGENT) == g)
                __builtin_amdgcn_s_sleep(2);
        }
        __threadfence();     // acquire: invalidate stale local caches
    }
    __syncthreads();
}

// ---------------- single persistent mega-kernel (plain launch) --------------
// ctrl[0]=barrier cnt, ctrl[1]=barrier gen, ctrl[2]=work ctr L0, ctrl[3]=L1
// stage 1 (grid-strided): edge-scatter | weight-pack | transpose->bf16
// stage 2/3: per-wave work-stolen 16-row tiles: gather+mean (LDS) + MFMA GEMM

__global__ __launch_bounds__(256, 2) void k_mega(
        const float4* __restrict__ feat, const int* __restrict__ src,
        const int* __restrict__ dst, const float* __restrict__ Wself,
        const float* __restrict__ Wneigh, const float* __restrict__ bias,
        unsigned short* __restrict__ h0, unsigned short* __restrict__ h1,
        unsigned short* __restrict__ Wp, int* __restrict__ cursor,
        int* __restrict__ bucket, int* __restrict__ ctrl,
        float* __restrict__ out) {
    const int tid = threadIdx.x;
    const int blk = blockIdx.x;          // 0..511

    // ---- stage 1: scatter / pack / transpose, grid-strided ----
    for (int c = blk; c < 5657; c += GRID) {
        if (c < 625) {
            int e = c * 256 + tid;       // E_ == 625*256 exactly
            int d = dst[e];
            int p = atomicAdd(&cursor[d], 1);
            if (p < CAP) bucket[d * CAP + p] = src[e];
        } else if (c < 657) {
            int t = (c - 625) * 256 + tid;
            int mat = t >> 11;
            int r = t & 2047;
            int kb = r >> 9;
            int nb = (r >> 6) & 7;
            int lane = r & 63;
            int l = mat >> 1, s = mat & 1;
            const float* W = (s ? Wneigh : Wself) + (size_t)l * F_ * F_;
            int k0 = kb * 32 + (lane >> 4) * 8;
            int n  = nb * 16 + (lane & 15);
            unsigned short* dstp = Wp + (size_t)mat * 16384 +
                                   (size_t)((kb * 8 + nb) * 64 + lane) * 8;
#pragma unroll
            for (int j = 0; j < 8; j++) dstp[j] = f2bf(W[(size_t)(k0 + j) * F_ + n]);
        } else {
            int i = (c - 657) * 256 + tid;   // over M_*32 float4s
            int f4 = i & 31;
            int m  = i >> 5;                 // m = n*BT_ + bt
            int n  = m >> 2;
            int bt = m & 3;
            float4 v = feat[(bt * N_ + n) * 32 + f4];
            ushort4 o;
            o.x = f2bf(v.x); o.y = f2bf(v.y); o.z = f2bf(v.z); o.w = f2bf(v.w);
            *(ushort4*)(h0 + (size_t)m * 128 + f4 * 4) = o;
        }
    }
    gridbar(ctrl, ctrl + 1);

    // ---- stages 2/3: fused layers, per-wave work-stolen 16-row tiles ----
    // [wave][node_local][bt][128+8] — pad keeps ds_read_b128 bank-uniform.
    // Each wave touches only aggs[wave] -> no intra-block sync needed.
    __shared__ unsigned short aggs[4][4][4][136];
    const int wave = tid >> 6, lane = tid & 63;
    const int col  = lane & 15;
    const int quad = lane >> 4;

    for (int l = 0; l < 2; l++) {
        const unsigned short* hin = l ? h1 : h0;
        const unsigned short* B0  = Wp + (size_t)l * 2 * 16384 + (size_t)lane * 8;
        const unsigned short* B1  = B0 + 16384;
        const float* bL = bias + l * F_;
        int* wc = ctrl + 2 + l;

        for (;;) {
            int wt;
            if (lane == 0)
                wt = __hip_atomic_fetch_add(wc, 1, __ATOMIC_RELAXED,
                                            __HIP_MEMORY_SCOPE_AGENT);
            wt = __builtin_amdgcn_readfirstlane(wt);
            if (wt >= WT_) break;

            const int m0 = wt * 16;
            const int node0 = m0 >> 2;

            // phase A: aggregate this wave's 4 nodes into its LDS patch
#pragma unroll
            for (int nl = 0; nl < 4; nl++) {
                const int n = node0 + nl;
                const int deg = cursor[n];
                const int nn = deg < CAP ? deg : CAP;
                float acc[8] = {0, 0, 0, 0, 0, 0, 0, 0};
                int idx = bucket[n * CAP + (lane < nn ? lane : 0)];  // coalesced
#pragma unroll 8
                for (int e = 0; e < nn; e++) {
                    int s = __builtin_amdgcn_readlane(idx, e);   // SGPR, no mem op
                    u16x8 a = *(const u16x8*)(hin + (size_t)s * 512 + lane * 8);
#pragma unroll
                    for (int j = 0; j < 8; j++) acc[j] += bf2f(a[j]);
                }
                float w = (deg > 0) ? 1.0f / (float)deg : 0.0f;
                u16x8 o;
#pragma unroll
                for (int j = 0; j < 8; j++) o[j] = f2bf(acc[j] * w);
                *(u16x8*)&aggs[wave][nl][lane >> 4][(lane & 15) * 8] = o;
            }

            // phase B: double GEMM
            f32x4 acc[8];
#pragma unroll
            for (int nb = 0; nb < 8; nb++) {
                float b = bL[nb * 16 + col];
                acc[nb] = (f32x4){b, b, b, b};
            }

            const unsigned short* A0 = hin + (size_t)(m0 + col) * 128 + quad * 8;
            const unsigned short* As = &aggs[wave][col >> 2][col & 3][quad * 8];

#pragma unroll
            for (int kb = 0; kb < 4; kb++) {
                bf16x8 a = *(const bf16x8*)(A0 + kb * 32);
#pragma unroll
                for (int nb = 0; nb < 8; nb++) {
                    bf16x8 b = *(const bf16x8*)(B0 + (size_t)((kb * 8 + nb) * 64) * 8);
                    acc[nb] = __builtin_amdgcn_mfma_f32_16x16x32_bf16(a, b, acc[nb], 0, 0, 0);
                }
            }
#pragma unroll
            for (int kb = 0; kb < 4; kb++) {
                bf16x8 a = *(const bf16x8*)(As + kb * 32);   // LDS
#pragma unroll
                for (int nb = 0; nb < 8; nb++) {
                    bf16x8 b = *(const bf16x8*)(B1 + (size_t)((kb * 8 + nb) * 64) * 8);
                    acc[nb] = __builtin_amdgcn_mfma_f32_16x16x32_bf16(a, b, acc[nb], 0, 0, 0);
                }
            }

            if (l == 0) {
#pragma unroll
                for (int nb = 0; nb < 8; nb++) {
#pragma unroll
                    for (int r = 0; r < 4; r++) {
                        int m = m0 + quad * 4 + r;
                        h1[(size_t)m * 128 + nb * 16 + col] = f2bf(acc[nb][r]);
                    }
                }
            } else {
#pragma unroll
                for (int nb = 0; nb < 8; nb++) {
#pragma unroll
                    for (int r = 0; r < 4; r++) {
                        int m = m0 + quad * 4 + r;
                        int node = m >> 2, bt = m & 3;
                        out[((size_t)bt * N_ + node) * 128 + nb * 16 + col] = acc[nb][r];
                    }
                }
            }
        }
        if (l == 0) gridbar(ctrl, ctrl + 1);   // h1 complete before layer-1 gathers
    }
}

// ---------------- launch ----------------

extern "C" void kernel_launch(void* const* d_in, const int* in_sizes, int n_in,
                              void* d_out, int out_size, void* d_ws, size_t ws_size,
                              hipStream_t stream) {
    const float4* feature = (const float4*)d_in[0];   // [B,T,N,F]
    const float*  W_self  = (const float*)d_in[1];    // [L,F,F]
    const float*  W_neigh = (const float*)d_in[2];    // [L,F,F]
    const float*  bias    = (const float*)d_in[3];    // [L,F]
    const int*    e_src   = (const int*)d_in[4];      // [E]
    const int*    e_dst   = (const int*)d_in[5];      // [E]
    float*        out     = (float*)d_out;            // [B,T,N,F]

    char* ws = (char*)d_ws;
    unsigned short* h0   = (unsigned short*)ws;  ws += (size_t)M_ * F_ * 2;   // 10.24 MB
    unsigned short* h1   = (unsigned short*)ws;  ws += (size_t)M_ * F_ * 2;
    unsigned short* Wp   = (unsigned short*)ws;  ws += (size_t)4 * 16384 * 2; // 128 KB
    int*   cursor  = (int*)ws;                   ws += (size_t)N_ * 4;        // zeroed
    int*   ctrl    = (int*)ws;                   ws += 4 * 4;                 // zeroed
    int*   bucket  = (int*)ws;                   ws += (size_t)N_ * CAP * 4;  // 2.56 MB

    // zero cursor + ctrl (cnt, gen, wc0, wc1) in one memset
    hipMemsetAsync(cursor, 0, (size_t)N_ * 4 + 16, stream);

    k_mega<<<GRID, 256, 0, stream>>>(feature, e_src, e_dst, W_self, W_neigh,
                                     bias, h0, h1, Wp, cursor, bucket, ctrl, out);
}

// Round 9
// 169.373 us; speedup vs baseline: 2.7766x; 2.7766x over previous
//
#include <hip/hip_runtime.h>

constexpr int N_  = 10000;
constexpr int F_  = 128;
constexpr int E_  = 160000;
constexpr int BT_ = 4;            // B*T
constexpr int M_  = N_ * BT_;     // 40000 rows of [F]
constexpr int CAP = 64;           // bucket capacity per node (deg ~ Poisson(16))

typedef __attribute__((ext_vector_type(8))) short bf16x8;   // 8 bf16 in 4 VGPRs
typedef __attribute__((ext_vector_type(4))) float f32x4;
typedef __attribute__((ext_vector_type(8))) unsigned short u16x8;

static __device__ inline float bf2f(unsigned short u) {
    union { unsigned int i; float f; } v; v.i = ((unsigned int)u) << 16; return v.f;
}
static __device__ inline unsigned short f2bf(float f) {
    union { float f; unsigned int i; } v; v.f = f;
    unsigned int x = v.i;
    return (unsigned short)((x + 0x7fffu + ((x >> 16) & 1u)) >> 16);  // RNE
}

// ---------- fused prep: edge-scatter + weight-pack + transpose ----------
// blocks [0,625):    scatter edges into fixed-capacity buckets (count fused)
// blocks [625,657):  pack W into MFMA B-fragment layout
// blocks [657,5657): transpose [B,T,N,F] fp32 -> [N*BT, F] bf16

__global__ __launch_bounds__(256) void k_pre(const float4* __restrict__ feat,
        unsigned short* __restrict__ h0, const int* __restrict__ src,
        const int* __restrict__ dst, int* __restrict__ cursor,
        int* __restrict__ bucket, const float* __restrict__ Wself,
        const float* __restrict__ Wneigh, unsigned short* __restrict__ Wp) {
    const int b = blockIdx.x;
    const int tid = threadIdx.x;
    if (b < 625) {
        int e = b * 256 + tid;           // E_ == 625*256 exactly
        int d = dst[e];
        int p = atomicAdd(&cursor[d], 1);
        if (p < CAP) bucket[d * CAP + p] = src[e];
    } else if (b < 657) {
        int t = (b - 625) * 256 + tid;
        int mat = t >> 11;
        int r = t & 2047;
        int kb = r >> 9;
        int nb = (r >> 6) & 7;
        int lane = r & 63;
        int l = mat >> 1, s = mat & 1;
        const float* W = (s ? Wneigh : Wself) + (size_t)l * F_ * F_;
        int k0 = kb * 32 + (lane >> 4) * 8;
        int n  = nb * 16 + (lane & 15);
        unsigned short* dstp = Wp + (size_t)mat * 16384 +
                               (size_t)((kb * 8 + nb) * 64 + lane) * 8;
#pragma unroll
        for (int j = 0; j < 8; j++) dstp[j] = f2bf(W[(size_t)(k0 + j) * F_ + n]);
    } else {
        int i = (b - 657) * 256 + tid;   // over M_*32 float4s
        int f4 = i & 31;
        int m  = i >> 5;                 // m = n*BT_ + bt
        int n  = m >> 2;
        int bt = m & 3;
        float4 v = feat[(bt * N_ + n) * 32 + f4];
        ushort4 o;
        o.x = f2bf(v.x); o.y = f2bf(v.y); o.z = f2bf(v.z); o.w = f2bf(v.w);
        *(ushort4*)(h0 + (size_t)m * 128 + f4 * 4) = o;
    }
}

// ---------- fused layer: per-wave aggregation (LDS) + double-MFMA GEMM ------
// Block = 2 waves x 16 rows = 32 rows = 8 nodes (finer grid: 1250 blocks ->
// ~4.9 blocks/CU for balance + gather-latency hiding). Wave w owns 4 nodes,
// aggregates them into its private LDS patch (no __syncthreads needed), then
// computes out[m0..m0+15][:] = h*Wself + agg*Wneigh + b.

template <bool LAST>
__global__ __launch_bounds__(128) void k_fused(const unsigned short* __restrict__ h,
        const int* __restrict__ cursor, const int* __restrict__ bucket,
        const unsigned short* __restrict__ Wp, const float* __restrict__ bias,
        void* __restrict__ outv) {
    // [wave][node_local][bt][128+8] — pad keeps ds_read_b128 bank-uniform
    __shared__ unsigned short aggs[2][4][4][136];
    const int tid  = threadIdx.x;
    const int wave = tid >> 6, lane = tid & 63;
    const int m0   = blockIdx.x * 32 + wave * 16;
    const int node0 = m0 >> 2;
    const int col  = lane & 15;
    const int quad = lane >> 4;

    // ---- phase A: aggregate 4 nodes into LDS ----
#pragma unroll
    for (int nl = 0; nl < 4; nl++) {
        const int n = node0 + nl;
        const int deg = cursor[n];
        const int nn = deg < CAP ? deg : CAP;
        float acc[8] = {0, 0, 0, 0, 0, 0, 0, 0};
        int idx = bucket[n * CAP + (lane < nn ? lane : 0)];   // coalesced preload
#pragma unroll 8
        for (int e = 0; e < nn; e++) {
            int s = __builtin_amdgcn_readlane(idx, e);        // SGPR, no mem op
            u16x8 a = *(const u16x8*)(h + (size_t)s * 512 + lane * 8);
#pragma unroll
            for (int j = 0; j < 8; j++) acc[j] += bf2f(a[j]);
        }
        float w = (deg > 0) ? 1.0f / (float)deg : 0.0f;
        u16x8 o;
#pragma unroll
        for (int j = 0; j < 8; j++) o[j] = f2bf(acc[j] * w);
        // lane covers (bt = lane>>4, f = (lane&15)*8 .. +8)
        *(u16x8*)&aggs[wave][nl][lane >> 4][(lane & 15) * 8] = o;
    }

    // ---- phase B: double GEMM (wave-private LDS patch -> no barrier) ----
    f32x4 acc[8];
#pragma unroll
    for (int nb = 0; nb < 8; nb++) {
        float b = bias[nb * 16 + col];
        acc[nb] = (f32x4){b, b, b, b};
    }

    const unsigned short* A0 = h + (size_t)(m0 + col) * 128 + quad * 8;
    const unsigned short* As = &aggs[wave][col >> 2][col & 3][quad * 8];
    const unsigned short* B0 = Wp + (size_t)lane * 8;
    const unsigned short* B1 = B0 + 16384;

#pragma unroll
    for (int kb = 0; kb < 4; kb++) {
        bf16x8 a = *(const bf16x8*)(A0 + kb * 32);
#pragma unroll
        for (int nb = 0; nb < 8; nb++) {
            bf16x8 b = *(const bf16x8*)(B0 + (size_t)((kb * 8 + nb) * 64) * 8);
            acc[nb] = __builtin_amdgcn_mfma_f32_16x16x32_bf16(a, b, acc[nb], 0, 0, 0);
        }
    }
#pragma unroll
    for (int kb = 0; kb < 4; kb++) {
        bf16x8 a = *(const bf16x8*)(As + kb * 32);   // LDS
#pragma unroll
        for (int nb = 0; nb < 8; nb++) {
            bf16x8 b = *(const bf16x8*)(B1 + (size_t)((kb * 8 + nb) * 64) * 8);
            acc[nb] = __builtin_amdgcn_mfma_f32_16x16x32_bf16(a, b, acc[nb], 0, 0, 0);
        }
    }

    if (LAST) {
        float* out = (float*)outv;
#pragma unroll
        for (int nb = 0; nb < 8; nb++) {
#pragma unroll
            for (int r = 0; r < 4; r++) {
                int m = m0 + quad * 4 + r;
                int node = m >> 2, bt = m & 3;
                out[((size_t)bt * N_ + node) * 128 + nb * 16 + col] = acc[nb][r];
            }
        }
    } else {
        unsigned short* out = (unsigned short*)outv;
#pragma unroll
        for (int nb = 0; nb < 8; nb++) {
#pragma unroll
            for (int r = 0; r < 4; r++) {
                int m = m0 + quad * 4 + r;
                out[(size_t)m * 128 + nb * 16 + col] = f2bf(acc[nb][r]);
            }
        }
    }
}

// ---------------- launch ----------------

extern "C" void kernel_launch(void* const* d_in, const int* in_sizes, int n_in,
                              void* d_out, int out_size, void* d_ws, size_t ws_size,
                              hipStream_t stream) {
    const float* feature = (const float*)d_in[0];   // [B,T,N,F]
    const float* W_self  = (const float*)d_in[1];   // [L,F,F]
    const float* W_neigh = (const float*)d_in[2];   // [L,F,F]
    const float* bias    = (const float*)d_in[3];   // [L,F]
    const int*   e_src   = (const int*)d_in[4];     // [E]
    const int*   e_dst   = (const int*)d_in[5];     // [E]
    float*       out     = (float*)d_out;           // [B,T,N,F]

    char* ws = (char*)d_ws;
    unsigned short* h0   = (unsigned short*)ws;  ws += (size_t)M_ * F_ * 2;   // 10.24 MB
    unsigned short* h1   = (unsigned short*)ws;  ws += (size_t)M_ * F_ * 2;
    unsigned short* Wp   = (unsigned short*)ws;  ws += (size_t)4 * 16384 * 2; // 128 KB
    int*   cursor  = (int*)ws;                   ws += (size_t)N_ * 4;
    int*   bucket  = (int*)ws;                   ws += (size_t)N_ * CAP * 4;  // 2.56 MB

    hipMemsetAsync(cursor, 0, (size_t)N_ * 4, stream);

    k_pre<<<5657, 256, 0, stream>>>((const float4*)feature, h0, e_src, e_dst,
                                    cursor, bucket, W_self, W_neigh, Wp);

    const int gb = M_ / 32;               // 1250
    k_fused<false><<<gb, 128, 0, stream>>>(h0, cursor, bucket, Wp, bias, h1);
    k_fused<true><<<gb, 128, 0, stream>>>(h1, cursor, bucket, Wp + 2 * 16384,
                                          bias + F_, out);
}

// Round 10
// 165.785 us; speedup vs baseline: 2.8367x; 1.0216x over previous
//
#include <hip/hip_runtime.h>

constexpr int N_  = 10000;
constexpr int F_  = 128;
constexpr int E_  = 160000;
constexpr int BT_ = 4;            // B*T
constexpr int M_  = N_ * BT_;     // 40000 rows of [F]
constexpr int CAP = 64;           // bucket capacity per node (deg ~ Poisson(16))

typedef __attribute__((ext_vector_type(8))) short bf16x8;   // 8 bf16 in 4 VGPRs
typedef __attribute__((ext_vector_type(4))) float f32x4;
typedef __attribute__((ext_vector_type(2))) float f32x2;
typedef __attribute__((ext_vector_type(8))) unsigned short u16x8;

static __device__ inline float bf2f(unsigned short u) {
    union { unsigned int i; float f; } v; v.i = ((unsigned int)u) << 16; return v.f;
}
static __device__ inline unsigned short f2bf(float f) {
    union { float f; unsigned int i; } v; v.f = f;
    unsigned int x = v.i;
    return (unsigned short)((x + 0x7fffu + ((x >> 16) & 1u)) >> 16);  // RNE
}

// ---------- fused prep: edge-scatter + weight-pack + transpose ----------
// blocks [0,625):    scatter edges into fixed-capacity buckets (count fused)
// blocks [625,657):  pack W into MFMA B-fragment layout
// blocks [657,5657): transpose [B,T,N,F] fp32 -> [N*BT,F] bf16 + fp8 shadow

__global__ __launch_bounds__(256) void k_pre(const float4* __restrict__ feat,
        unsigned short* __restrict__ h0, unsigned char* __restrict__ h8,
        const int* __restrict__ src, const int* __restrict__ dst,
        int* __restrict__ cursor, int* __restrict__ bucket,
        const float* __restrict__ Wself, const float* __restrict__ Wneigh,
        unsigned short* __restrict__ Wp) {
    const int b = blockIdx.x;
    const int tid = threadIdx.x;
    if (b < 625) {
        int e = b * 256 + tid;           // E_ == 625*256 exactly
        int d = dst[e];
        int p = atomicAdd(&cursor[d], 1);
        if (p < CAP) bucket[d * CAP + p] = src[e];
    } else if (b < 657) {
        int t = (b - 625) * 256 + tid;
        int mat = t >> 11;
        int r = t & 2047;
        int kb = r >> 9;
        int nb = (r >> 6) & 7;
        int lane = r & 63;
        int l = mat >> 1, s = mat & 1;
        const float* W = (s ? Wneigh : Wself) + (size_t)l * F_ * F_;
        int k0 = kb * 32 + (lane >> 4) * 8;
        int n  = nb * 16 + (lane & 15);
        unsigned short* dstp = Wp + (size_t)mat * 16384 +
                               (size_t)((kb * 8 + nb) * 64 + lane) * 8;
#pragma unroll
        for (int j = 0; j < 8; j++) dstp[j] = f2bf(W[(size_t)(k0 + j) * F_ + n]);
    } else {
        int i = (b - 657) * 256 + tid;   // over M_*32 float4s
        int f4 = i & 31;
        int m  = i >> 5;                 // m = n*BT_ + bt
        int n  = m >> 2;
        int bt = m & 3;
        float4 v = feat[(bt * N_ + n) * 32 + f4];
        ushort4 o;
        o.x = f2bf(v.x); o.y = f2bf(v.y); o.z = f2bf(v.z); o.w = f2bf(v.w);
        *(ushort4*)(h0 + (size_t)m * 128 + f4 * 4) = o;
        // fp8 e4m3 shadow for layer-0 gather (RNE hw converter)
        int w0 = __builtin_amdgcn_cvt_pk_fp8_f32(v.x, v.y, 0, false);
        int w1 = __builtin_amdgcn_cvt_pk_fp8_f32(v.z, v.w, w0, true);
        *(unsigned int*)(h8 + (size_t)m * 128 + f4 * 4) = (unsigned int)w1;
    }
}

// ---------- fused layer: per-wave aggregation (LDS) + double-MFMA GEMM ------
// Block = 2 waves x 16 rows = 8 nodes; 1250 blocks for balance/latency hiding.
// FP8GATHER: phase A reads the fp8 shadow (half traffic, ~L2-resident).
// Node n: bf16 row-group at h + n*512 elems (1 KB); fp8 at h8 + n*512 bytes.

template <bool LAST, bool FP8GATHER>
__global__ __launch_bounds__(128) void k_fused(const unsigned short* __restrict__ h,
        const unsigned char* __restrict__ h8, const int* __restrict__ cursor,
        const int* __restrict__ bucket, const unsigned short* __restrict__ Wp,
        const float* __restrict__ bias, void* __restrict__ outv) {
    // [wave][node_local][bt][128+8] — pad keeps ds_read_b128 bank-uniform
    __shared__ unsigned short aggs[2][4][4][136];
    const int tid  = threadIdx.x;
    const int wave = tid >> 6, lane = tid & 63;
    const int m0   = blockIdx.x * 32 + wave * 16;
    const int node0 = m0 >> 2;
    const int col  = lane & 15;
    const int quad = lane >> 4;

    // ---- phase A: aggregate 4 nodes into LDS ----
#pragma unroll
    for (int nl = 0; nl < 4; nl++) {
        const int n = node0 + nl;
        const int deg = cursor[n];
        const int nn = deg < CAP ? deg : CAP;
        float acc[8] = {0, 0, 0, 0, 0, 0, 0, 0};
        int idx = bucket[n * CAP + (lane < nn ? lane : 0)];   // coalesced preload
#pragma unroll 8
        for (int e = 0; e < nn; e++) {
            int s = __builtin_amdgcn_readlane(idx, e);        // SGPR, no mem op
            if (FP8GATHER) {
                uint2 a8 = *(const uint2*)(h8 + (size_t)s * 512 + lane * 8);
                f32x2 p0 = __builtin_amdgcn_cvt_pk_f32_fp8(a8.x, false);
                f32x2 p1 = __builtin_amdgcn_cvt_pk_f32_fp8(a8.x, true);
                f32x2 p2 = __builtin_amdgcn_cvt_pk_f32_fp8(a8.y, false);
                f32x2 p3 = __builtin_amdgcn_cvt_pk_f32_fp8(a8.y, true);
                acc[0] += p0.x; acc[1] += p0.y; acc[2] += p1.x; acc[3] += p1.y;
                acc[4] += p2.x; acc[5] += p2.y; acc[6] += p3.x; acc[7] += p3.y;
            } else {
                u16x8 a = *(const u16x8*)(h + (size_t)s * 512 + lane * 8);
#pragma unroll
                for (int j = 0; j < 8; j++) acc[j] += bf2f(a[j]);
            }
        }
        float w = (deg > 0) ? 1.0f / (float)deg : 0.0f;
        u16x8 o;
#pragma unroll
        for (int j = 0; j < 8; j++) o[j] = f2bf(acc[j] * w);
        // lane covers (bt = lane>>4, f = (lane&15)*8 .. +8)
        *(u16x8*)&aggs[wave][nl][lane >> 4][(lane & 15) * 8] = o;
    }

    // ---- phase B: double GEMM (wave-private LDS patch -> no barrier) ----
    f32x4 acc[8];
#pragma unroll
    for (int nb = 0; nb < 8; nb++) {
        float b = bias[nb * 16 + col];
        acc[nb] = (f32x4){b, b, b, b};
    }

    const unsigned short* A0 = h + (size_t)(m0 + col) * 128 + quad * 8;
    const unsigned short* As = &aggs[wave][col >> 2][col & 3][quad * 8];
    const unsigned short* B0 = Wp + (size_t)lane * 8;
    const unsigned short* B1 = B0 + 16384;

#pragma unroll
    for (int kb = 0; kb < 4; kb++) {
        bf16x8 a = *(const bf16x8*)(A0 + kb * 32);
#pragma unroll
        for (int nb = 0; nb < 8; nb++) {
            bf16x8 b = *(const bf16x8*)(B0 + (size_t)((kb * 8 + nb) * 64) * 8);
            acc[nb] = __builtin_amdgcn_mfma_f32_16x16x32_bf16(a, b, acc[nb], 0, 0, 0);
        }
    }
#pragma unroll
    for (int kb = 0; kb < 4; kb++) {
        bf16x8 a = *(const bf16x8*)(As + kb * 32);   // LDS
#pragma unroll
        for (int nb = 0; nb < 8; nb++) {
            bf16x8 b = *(const bf16x8*)(B1 + (size_t)((kb * 8 + nb) * 64) * 8);
            acc[nb] = __builtin_amdgcn_mfma_f32_16x16x32_bf16(a, b, acc[nb], 0, 0, 0);
        }
    }

    if (LAST) {
        float* out = (float*)outv;
#pragma unroll
        for (int nb = 0; nb < 8; nb++) {
#pragma unroll
            for (int r = 0; r < 4; r++) {
                int m = m0 + quad * 4 + r;
                int node = m >> 2, bt = m & 3;
                out[((size_t)bt * N_ + node) * 128 + nb * 16 + col] = acc[nb][r];
            }
        }
    } else {
        unsigned short* out = (unsigned short*)outv;
#pragma unroll
        for (int nb = 0; nb < 8; nb++) {
#pragma unroll
            for (int r = 0; r < 4; r++) {
                int m = m0 + quad * 4 + r;
                out[(size_t)m * 128 + nb * 16 + col] = f2bf(acc[nb][r]);
            }
        }
    }
}

// ---------------- launch ----------------

extern "C" void kernel_launch(void* const* d_in, const int* in_sizes, int n_in,
                              void* d_out, int out_size, void* d_ws, size_t ws_size,
                              hipStream_t stream) {
    const float* feature = (const float*)d_in[0];   // [B,T,N,F]
    const float* W_self  = (const float*)d_in[1];   // [L,F,F]
    const float* W_neigh = (const float*)d_in[2];   // [L,F,F]
    const float* bias    = (const float*)d_in[3];   // [L,F]
    const int*   e_src   = (const int*)d_in[4];     // [E]
    const int*   e_dst   = (const int*)d_in[5];     // [E]
    float*       out     = (float*)d_out;           // [B,T,N,F]

    char* ws = (char*)d_ws;
    unsigned short* h0   = (unsigned short*)ws;  ws += (size_t)M_ * F_ * 2;   // 10.24 MB
    unsigned short* h1   = (unsigned short*)ws;  ws += (size_t)M_ * F_ * 2;
    unsigned char*  h8   = (unsigned char*)ws;   ws += (size_t)M_ * F_;       // 5.12 MB
    unsigned short* Wp   = (unsigned short*)ws;  ws += (size_t)4 * 16384 * 2; // 128 KB
    int*   cursor  = (int*)ws;                   ws += (size_t)N_ * 4;
    int*   bucket  = (int*)ws;                   ws += (size_t)N_ * CAP * 4;  // 2.56 MB

    hipMemsetAsync(cursor, 0, (size_t)N_ * 4, stream);

    k_pre<<<5657, 256, 0, stream>>>((const float4*)feature, h0, h8, e_src,
                                    e_dst, cursor, bucket, W_self, W_neigh, Wp);

    const int gb = M_ / 32;               // 1250
    // layer 0: fp8 gather from h8 shadow
    k_fused<false, true><<<gb, 128, 0, stream>>>(h0, h8, cursor, bucket, Wp,
                                                 bias, h1);
    // layer 1: bf16 gather from h1
    k_fused<true, false><<<gb, 128, 0, stream>>>(h1, nullptr, cursor, bucket,
                                                 Wp + 2 * 16384, bias + F_, out);
}

// Round 11
// 164.129 us; speedup vs baseline: 2.8654x; 1.0101x over previous
//
#include <hip/hip_runtime.h>

constexpr int N_  = 10000;
constexpr int F_  = 128;
constexpr int E_  = 160000;
constexpr int BT_ = 4;            // B*T
constexpr int M_  = N_ * BT_;     // 40000 rows of [F]
constexpr int CAP = 64;           // bucket capacity per node (deg ~ Poisson(16))

typedef __attribute__((ext_vector_type(8))) short bf16x8;   // 8 bf16 in 4 VGPRs
typedef __attribute__((ext_vector_type(4))) float f32x4;
typedef __attribute__((ext_vector_type(2))) float f32x2;
typedef __attribute__((ext_vector_type(8))) unsigned short u16x8;

static __device__ inline float bf2f(unsigned short u) {
    union { unsigned int i; float f; } v; v.i = ((unsigned int)u) << 16; return v.f;
}
static __device__ inline unsigned short f2bf(float f) {
    union { float f; unsigned int i; } v; v.f = f;
    unsigned int x = v.i;
    return (unsigned short)((x + 0x7fffu + ((x >> 16) & 1u)) >> 16);  // RNE
}

// ---------- fused prep: edge-scatter + weight-pack + transpose ----------
// blocks [0,625):    scatter edges into fixed-capacity buckets (count fused)
// blocks [625,657):  pack W into MFMA B-fragment layout
// blocks [657,5657): transpose [B,T,N,F] fp32 -> [N*BT,F] bf16 + fp8 shadow

__global__ __launch_bounds__(256) void k_pre(const float4* __restrict__ feat,
        unsigned short* __restrict__ h0, unsigned char* __restrict__ h8,
        const int* __restrict__ src, const int* __restrict__ dst,
        int* __restrict__ cursor, int* __restrict__ bucket,
        const float* __restrict__ Wself, const float* __restrict__ Wneigh,
        unsigned short* __restrict__ Wp) {
    const int b = blockIdx.x;
    const int tid = threadIdx.x;
    if (b < 625) {
        int e = b * 256 + tid;           // E_ == 625*256 exactly
        int d = dst[e];
        int p = atomicAdd(&cursor[d], 1);
        if (p < CAP) bucket[d * CAP + p] = src[e];
    } else if (b < 657) {
        int t = (b - 625) * 256 + tid;
        int mat = t >> 11;
        int r = t & 2047;
        int kb = r >> 9;
        int nb = (r >> 6) & 7;
        int lane = r & 63;
        int l = mat >> 1, s = mat & 1;
        const float* W = (s ? Wneigh : Wself) + (size_t)l * F_ * F_;
        int k0 = kb * 32 + (lane >> 4) * 8;
        int n  = nb * 16 + (lane & 15);
        unsigned short* dstp = Wp + (size_t)mat * 16384 +
                               (size_t)((kb * 8 + nb) * 64 + lane) * 8;
#pragma unroll
        for (int j = 0; j < 8; j++) dstp[j] = f2bf(W[(size_t)(k0 + j) * F_ + n]);
    } else {
        int i = (b - 657) * 256 + tid;   // over M_*32 float4s
        int f4 = i & 31;
        int m  = i >> 5;                 // m = n*BT_ + bt
        int n  = m >> 2;
        int bt = m & 3;
        float4 v = feat[(bt * N_ + n) * 32 + f4];
        ushort4 o;
        o.x = f2bf(v.x); o.y = f2bf(v.y); o.z = f2bf(v.z); o.w = f2bf(v.w);
        *(ushort4*)(h0 + (size_t)m * 128 + f4 * 4) = o;
        // fp8 e4m3 shadow for layer-0 gather (RNE hw converter)
        int w0 = __builtin_amdgcn_cvt_pk_fp8_f32(v.x, v.y, 0, false);
        int w1 = __builtin_amdgcn_cvt_pk_fp8_f32(v.z, v.w, w0, true);
        *(unsigned int*)(h8 + (size_t)m * 128 + f4 * 4) = (unsigned int)w1;
    }
}

// ---------- fused layer: per-wave fp8 aggregation (LDS) + double-MFMA GEMM --
// Block = 2 waves x 16 rows = 8 nodes; 1250 blocks for balance/latency hiding.
// Phase A always gathers the fp8 shadow g8 (node stride 512 B).
// LAST=false epilogue writes h1 (bf16) + its fp8 shadow for the next layer.

template <bool LAST>
__global__ __launch_bounds__(128) void k_fused(const unsigned short* __restrict__ h,
        const unsigned char* __restrict__ g8, unsigned char* __restrict__ s8out,
        const int* __restrict__ cursor, const int* __restrict__ bucket,
        const unsigned short* __restrict__ Wp, const float* __restrict__ bias,
        void* __restrict__ outv) {
    // [wave][node_local][bt][128+8] — pad keeps ds_read_b128 bank-uniform
    __shared__ unsigned short aggs[2][4][4][136];
    const int tid  = threadIdx.x;
    const int wave = tid >> 6, lane = tid & 63;
    const int m0   = blockIdx.x * 32 + wave * 16;
    const int node0 = m0 >> 2;
    const int col  = lane & 15;
    const int quad = lane >> 4;

    // ---- phase A: aggregate 4 nodes (fp8 gather) into LDS ----
#pragma unroll
    for (int nl = 0; nl < 4; nl++) {
        const int n = node0 + nl;
        const int deg = cursor[n];
        const int nn = deg < CAP ? deg : CAP;
        float acc[8] = {0, 0, 0, 0, 0, 0, 0, 0};
        int idx = bucket[n * CAP + (lane < nn ? lane : 0)];   // coalesced preload
#pragma unroll 8
        for (int e = 0; e < nn; e++) {
            int s = __builtin_amdgcn_readlane(idx, e);        // SGPR, no mem op
            uint2 a8 = *(const uint2*)(g8 + (size_t)s * 512 + lane * 8);
            f32x2 p0 = __builtin_amdgcn_cvt_pk_f32_fp8(a8.x, false);
            f32x2 p1 = __builtin_amdgcn_cvt_pk_f32_fp8(a8.x, true);
            f32x2 p2 = __builtin_amdgcn_cvt_pk_f32_fp8(a8.y, false);
            f32x2 p3 = __builtin_amdgcn_cvt_pk_f32_fp8(a8.y, true);
            acc[0] += p0.x; acc[1] += p0.y; acc[2] += p1.x; acc[3] += p1.y;
            acc[4] += p2.x; acc[5] += p2.y; acc[6] += p3.x; acc[7] += p3.y;
        }
        float w = (deg > 0) ? 1.0f / (float)deg : 0.0f;
        u16x8 o;
#pragma unroll
        for (int j = 0; j < 8; j++) o[j] = f2bf(acc[j] * w);
        // lane covers (bt = lane>>4, f = (lane&15)*8 .. +8)
        *(u16x8*)&aggs[wave][nl][lane >> 4][(lane & 15) * 8] = o;
    }

    // ---- phase B: double GEMM (wave-private LDS patch -> no barrier) ----
    f32x4 acc[8];
#pragma unroll
    for (int nb = 0; nb < 8; nb++) {
        float b = bias[nb * 16 + col];
        acc[nb] = (f32x4){b, b, b, b};
    }

    const unsigned short* A0 = h + (size_t)(m0 + col) * 128 + quad * 8;
    const unsigned short* As = &aggs[wave][col >> 2][col & 3][quad * 8];
    const unsigned short* B0 = Wp + (size_t)lane * 8;
    const unsigned short* B1 = B0 + 16384;

#pragma unroll
    for (int kb = 0; kb < 4; kb++) {
        bf16x8 a = *(const bf16x8*)(A0 + kb * 32);
#pragma unroll
        for (int nb = 0; nb < 8; nb++) {
            bf16x8 b = *(const bf16x8*)(B0 + (size_t)((kb * 8 + nb) * 64) * 8);
            acc[nb] = __builtin_amdgcn_mfma_f32_16x16x32_bf16(a, b, acc[nb], 0, 0, 0);
        }
    }
#pragma unroll
    for (int kb = 0; kb < 4; kb++) {
        bf16x8 a = *(const bf16x8*)(As + kb * 32);   // LDS
#pragma unroll
        for (int nb = 0; nb < 8; nb++) {
            bf16x8 b = *(const bf16x8*)(B1 + (size_t)((kb * 8 + nb) * 64) * 8);
            acc[nb] = __builtin_amdgcn_mfma_f32_16x16x32_bf16(a, b, acc[nb], 0, 0, 0);
        }
    }

    if (LAST) {
        float* out = (float*)outv;
#pragma unroll
        for (int nb = 0; nb < 8; nb++) {
#pragma unroll
            for (int r = 0; r < 4; r++) {
                int m = m0 + quad * 4 + r;
                int node = m >> 2, bt = m & 3;
                out[((size_t)bt * N_ + node) * 128 + nb * 16 + col] = acc[nb][r];
            }
        }
    } else {
        unsigned short* out = (unsigned short*)outv;
#pragma unroll
        for (int nb = 0; nb < 8; nb++) {
#pragma unroll
            for (int r = 0; r < 4; r++) {
                int m = m0 + quad * 4 + r;
                out[(size_t)m * 128 + nb * 16 + col] = f2bf(acc[nb][r]);
                // fp8 shadow of h1 for the layer-1 gather
                int p = __builtin_amdgcn_cvt_pk_fp8_f32(acc[nb][r], acc[nb][r],
                                                        0, false);
                s8out[(size_t)m * 128 + nb * 16 + col] = (unsigned char)(p & 0xff);
            }
        }
    }
}

// ---------------- launch ----------------

extern "C" void kernel_launch(void* const* d_in, const int* in_sizes, int n_in,
                              void* d_out, int out_size, void* d_ws, size_t ws_size,
                              hipStream_t stream) {
    const float* feature = (const float*)d_in[0];   // [B,T,N,F]
    const float* W_self  = (const float*)d_in[1];   // [L,F,F]
    const float* W_neigh = (const float*)d_in[2];   // [L,F,F]
    const float* bias    = (const float*)d_in[3];   // [L,F]
    const int*   e_src   = (const int*)d_in[4];     // [E]
    const int*   e_dst   = (const int*)d_in[5];     // [E]
    float*       out     = (float*)d_out;           // [B,T,N,F]

    char* ws = (char*)d_ws;
    unsigned short* h0   = (unsigned short*)ws;  ws += (size_t)M_ * F_ * 2;   // 10.24 MB
    unsigned short* h1   = (unsigned short*)ws;  ws += (size_t)M_ * F_ * 2;
    unsigned char*  h08  = (unsigned char*)ws;   ws += (size_t)M_ * F_;       // 5.12 MB
    unsigned char*  h18  = (unsigned char*)ws;   ws += (size_t)M_ * F_;       // 5.12 MB
    unsigned short* Wp   = (unsigned short*)ws;  ws += (size_t)4 * 16384 * 2; // 128 KB
    int*   cursor  = (int*)ws;                   ws += (size_t)N_ * 4;
    int*   bucket  = (int*)ws;                   ws += (size_t)N_ * CAP * 4;  // 2.56 MB

    hipMemsetAsync(cursor, 0, (size_t)N_ * 4, stream);

    k_pre<<<5657, 256, 0, stream>>>((const float4*)feature, h0, h08, e_src,
                                    e_dst, cursor, bucket, W_self, W_neigh, Wp);

    const int gb = M_ / 32;               // 1250
    // layer 0: fp8 gather from h08; writes h1 (bf16) + h18 (fp8 shadow)
    k_fused<false><<<gb, 128, 0, stream>>>(h0, h08, h18, cursor, bucket, Wp,
                                           bias, h1);
    // layer 1: fp8 gather from h18; writes fp32 out
    k_fused<true><<<gb, 128, 0, stream>>>(h1, h18, nullptr, cursor, bucket,
                                          Wp + 2 * 16384, bias + F_, out);
}